// Round 11
// baseline (195.982 us; speedup 1.0000x reference)
//
#include <hip/hip_runtime.h>
#include <math.h>
#include <stdint.h>

// DictNet: out = sparsity(C) + h2(class-pair mean dists) + h1(group mean dists)/beta
// 5 launches (R6 structure; prep-lhat = flat register version, no LDS, 32 waves/CU):
//  prep   : Lb = bf16(D*C) (flat, block-contiguous chunks) | xT | sort + 64-tile prefix
//  yhat   : yh = x - Lb@x (MFMA 64x64, BK=64, reg prefetch, XCD swizzle)
//  gather : ypb[p] = bf16(yh[perm[p]]) + row norms
//  classh1: per-class MFMA Gram dist sums (64x64 tri tiles) | h1 groups
//  final  : scalar assembly

#define TB 256

using short8 = __attribute__((ext_vector_type(8))) short;
using f32x4  = __attribute__((ext_vector_type(4))) float;

__device__ inline short f2bf(float f) {
  union { float f; unsigned u; } v; v.f = f;
  unsigned r = v.u + 0x7FFF + ((v.u >> 16) & 1);  // RNE
  return (short)(r >> 16);
}

// ---- fused prep ----
// blocks [0,nbG): flat lhat over pair-chunks (no LDS -> 8 blocks/CU streaming)
// blocks [nbG,nbG+nbX): xT 32x32 transpose tiles
// block nbG+nbX: sort (count/prefix/scatter) + 64-tile triangular prefix
__global__ __launch_bounds__(TB) void k_prep(
    const float* __restrict__ D, const float* __restrict__ Cv,
    const float* __restrict__ x, const int* __restrict__ y,
    const int* __restrict__ mask,
    short* __restrict__ Lb, short* __restrict__ xT,
    int* __restrict__ perm, int* __restrict__ cnt,
    int* __restrict__ start, int* __restrict__ tstart,
    float* __restrict__ S, float* __restrict__ h1,
    long long NP, int N, int d, long long CPB, int nbG, int nbX) {
  __shared__ float tile[32][33];          // xT branch only (~4.2 KB total)
  __shared__ int lcnt[8], lcur[8], lstart[8], ltile[8];
  const int b = blockIdx.x;
  const int t = threadIdx.x;
  if (b < nbG) {
    float cf[14];
#pragma unroll
    for (int f = 0; f < 14; ++f) cf[f] = Cv[f];
    long long i1 = (long long)b * CPB + CPB;
    if (i1 > NP) i1 = NP;
    for (long long i = (long long)b * CPB + t; i < i1; i += TB) {
      const float4* p = (const float4*)(D + i * 28);  // 112B/lane, 16B-aligned
      float4 v0 = p[0], v1 = p[1], v2 = p[2], v3 = p[3];
      float4 v4 = p[4], v5 = p[5], v6 = p[6];
      float d0 = v0.x * cf[0];
      d0 = fmaf(v0.y, cf[1], d0);  d0 = fmaf(v0.z, cf[2], d0);
      d0 = fmaf(v0.w, cf[3], d0);  d0 = fmaf(v1.x, cf[4], d0);
      d0 = fmaf(v1.y, cf[5], d0);  d0 = fmaf(v1.z, cf[6], d0);
      d0 = fmaf(v1.w, cf[7], d0);  d0 = fmaf(v2.x, cf[8], d0);
      d0 = fmaf(v2.y, cf[9], d0);  d0 = fmaf(v2.z, cf[10], d0);
      d0 = fmaf(v2.w, cf[11], d0); d0 = fmaf(v3.x, cf[12], d0);
      d0 = fmaf(v3.y, cf[13], d0);
      float d1 = v3.z * cf[0];
      d1 = fmaf(v3.w, cf[1], d1);  d1 = fmaf(v4.x, cf[2], d1);
      d1 = fmaf(v4.y, cf[3], d1);  d1 = fmaf(v4.z, cf[4], d1);
      d1 = fmaf(v4.w, cf[5], d1);  d1 = fmaf(v5.x, cf[6], d1);
      d1 = fmaf(v5.y, cf[7], d1);  d1 = fmaf(v5.z, cf[8], d1);
      d1 = fmaf(v5.w, cf[9], d1);  d1 = fmaf(v6.x, cf[10], d1);
      d1 = fmaf(v6.y, cf[11], d1); d1 = fmaf(v6.z, cf[12], d1);
      d1 = fmaf(v6.w, cf[13], d1);
      short2 o; o.x = f2bf(d0); o.y = f2bf(d1);
      *(short2*)(Lb + i * 2) = o;
    }
  } else if (b < nbG + nbX) {
    const int b2 = b - nbG;
    const int nbx = d >> 5;
    const int r0 = (b2 / nbx) * 32, c0 = (b2 % nbx) * 32;
    const int tx = t & 31, ty = t >> 5;  // 32 x 8
#pragma unroll
    for (int i = 0; i < 4; ++i) {
      int rr = r0 + ty + i * 8;
      tile[ty + i * 8][tx] = (rr < N) ? x[(size_t)rr * d + c0 + tx] : 0.f;
    }
    __syncthreads();
    if (r0 + tx < N) {
#pragma unroll
      for (int i = 0; i < 4; ++i) {
        int c = c0 + ty + i * 8;
        xT[(size_t)c * N + r0 + tx] = f2bf(tile[tx][ty + i * 8]);
      }
    }
  } else {
    if (t < 8) lcnt[t] = 0;
    if (t < 7) S[t] = 0.f;
    if (t == 0) h1[0] = 0.f;
    __syncthreads();
    for (int n = t; n < N; n += TB)
      if (mask[n] != 0) atomicAdd(&lcnt[y[n]], 1);
    __syncthreads();
    if (t == 0) {
      int s = 0;
      for (int c = 0; c < 7; ++c) { lstart[c] = s; lcur[c] = s; s += lcnt[c]; }
      lstart[7] = s;
      int tt = 0;
      for (int c = 0; c < 7; ++c) {
        int nb = (lcnt[c] + 63) >> 6;  // 64-row tiles
        ltile[c] = tt; tt += nb * (nb + 1) / 2;
      }
      ltile[7] = tt;
    }
    __syncthreads();
    for (int n = t; n < N; n += TB)
      if (mask[n] != 0) { int p = atomicAdd(&lcur[y[n]], 1); perm[p] = n; }
    if (t < 8) {
      start[t] = lstart[t];
      cnt[t] = (t < 7) ? lcnt[t] : 0;
      tstart[t] = ltile[t];
    }
  }
}

// yh = x - Lb @ x via bf16 MFMA. 64x64 tile, BK=64 (2 halves), register prefetch.
__global__ __launch_bounds__(TB) void k_yhat_mfma(
    const short* __restrict__ Lb, const short* __restrict__ xT,
    const float* __restrict__ x, float* __restrict__ yh, int N, int d) {
  __shared__ short As[2][64][40];
  __shared__ short Bs[2][64][40];
  const int nwg = gridDim.x;
  const int q = nwg >> 3, r = nwg & 7;
  const int xcd = blockIdx.x & 7, pos = blockIdx.x >> 3;
  const int wg = (xcd < r) ? xcd * (q + 1) + pos
                           : r * (q + 1) + (xcd - r) * q + pos;
  const int NCB = d >> 6;
  const int row0 = (wg / NCB) * 64, col0 = (wg % NCB) * 64;

  const int t = threadIdx.x;
  const int wid = t >> 6, lane = t & 63;
  const int wr = wid >> 1, wc = wid & 1;
  const int srow = t >> 2, skc = (t & 3) * 8;
  const int fr = lane & 15, fq = lane >> 4;

  const int grow = row0 + srow;
  const bool arow_ok = grow < N;
  const short* Lp = Lb + (size_t)grow * N + skc;
  const short* xp = xT + (size_t)(col0 + srow) * N + skc;

  const short8 z8 = {0, 0, 0, 0, 0, 0, 0, 0};
  const int KP = (N + 63) & ~63;

  short8 ca[2], cb[2];
#pragma unroll
  for (int h = 0; h < 2; ++h) {
    int k = h * 32;
    bool kok = (k + skc + 8 <= N);  // N%8==0: chunk all-valid or all-out
    ca[h] = (arow_ok && kok) ? *(const short8*)(Lp + k) : z8;
    cb[h] = kok ? *(const short8*)(xp + k) : z8;
  }

  f32x4 acc[2][2] = {};
  for (int k0 = 0; k0 < KP; k0 += 64) {
    short8 na[2] = {z8, z8}, nb[2] = {z8, z8};
    const int k1 = k0 + 64;
    if (k1 < KP) {
#pragma unroll
      for (int h = 0; h < 2; ++h) {
        int k = k1 + h * 32;
        bool kok = (k + skc + 8 <= N);
        if (arow_ok && kok) na[h] = *(const short8*)(Lp + k);
        if (kok) nb[h] = *(const short8*)(xp + k);
      }
    }
    __syncthreads();
    *(short8*)&As[0][srow][skc] = ca[0];
    *(short8*)&As[1][srow][skc] = ca[1];
    *(short8*)&Bs[0][srow][skc] = cb[0];
    *(short8*)&Bs[1][srow][skc] = cb[1];
    __syncthreads();
#pragma unroll
    for (int h = 0; h < 2; ++h) {
      short8 af[2], bf[2];
      af[0] = *(const short8*)&As[h][wr * 32 + fr][fq * 8];
      af[1] = *(const short8*)&As[h][wr * 32 + 16 + fr][fq * 8];
      bf[0] = *(const short8*)&Bs[h][wc * 32 + fr][fq * 8];
      bf[1] = *(const short8*)&Bs[h][wc * 32 + 16 + fr][fq * 8];
#pragma unroll
      for (int mi = 0; mi < 2; ++mi)
#pragma unroll
        for (int ni = 0; ni < 2; ++ni)
          acc[mi][ni] = __builtin_amdgcn_mfma_f32_16x16x32_bf16(
              af[mi], bf[ni], acc[mi][ni], 0, 0, 0);
    }
    ca[0] = na[0]; ca[1] = na[1]; cb[0] = nb[0]; cb[1] = nb[1];
  }
#pragma unroll
  for (int mi = 0; mi < 2; ++mi) {
#pragma unroll
    for (int j = 0; j < 4; ++j) {
      int m = row0 + wr * 32 + mi * 16 + fq * 4 + j;
      if (m >= N) continue;
#pragma unroll
      for (int ni = 0; ni < 2; ++ni) {
        int n = col0 + wc * 32 + ni * 16 + fr;
        float v = x[(size_t)m * d + n] - acc[mi][ni][j];
        yh[(size_t)m * d + n] = v;
      }
    }
  }
}

// ypb[p,:] = bf16(yh[perm[p],:]); sqp[p] = |row|^2. One wave per row.
__global__ __launch_bounds__(TB) void k_gather(const float* __restrict__ yh,
    const int* __restrict__ perm, const int* __restrict__ start,
    short* __restrict__ ypb, float* __restrict__ sqp, int d) {
  int p = blockIdx.x * 4 + (threadIdx.x >> 6);
  if (p >= start[7]) return;
  int lane = threadIdx.x & 63;
  int src = perm[p];
  const float4* in = (const float4*)(yh + (size_t)src * d);
  float4 v1 = in[lane * 2], v2 = in[lane * 2 + 1];
  float s = v1.x * v1.x + v1.y * v1.y + v1.z * v1.z + v1.w * v1.w
          + v2.x * v2.x + v2.y * v2.y + v2.z * v2.z + v2.w * v2.w;
  short8 o;
  o[0] = f2bf(v1.x); o[1] = f2bf(v1.y); o[2] = f2bf(v1.z); o[3] = f2bf(v1.w);
  o[4] = f2bf(v2.x); o[5] = f2bf(v2.y); o[6] = f2bf(v2.z); o[7] = f2bf(v2.w);
  *(short8*)(ypb + (size_t)p * d + lane * 8) = o;
#pragma unroll
  for (int off = 32; off > 0; off >>= 1) s += __shfl_down(s, off);
  if (lane == 0) sqp[p] = s;
}

// 1D grid: [0,G) h1 groups; [G, G+tri64) class Gram tiles via tstart. BK=64+prefetch.
__global__ __launch_bounds__(TB) void k_classh1(const short* __restrict__ ypb,
    const float* __restrict__ sqp, const int* __restrict__ start,
    const int* __restrict__ cnt, const int* __restrict__ tstart,
    const float* __restrict__ yh, const int* __restrict__ groups,
    float* __restrict__ S, float* __restrict__ h1, int d, int G) {
  __shared__ short As[2][64][40];
  __shared__ short Bs[2][64][40];
  __shared__ float wred[4];
  __shared__ float red[TB];
  const int t = threadIdx.x;
  const int b = blockIdx.x;

  if (b < G) {  // ---- h1 ----
    const int g = 7;
    const int* gi = groups + b * g;
    const int p = t >> 2, qq = t & 3;
    const int npair = g * g;
    float d2 = 0.f;
    if (p < npair) {
      const float4* A = (const float4*)(yh + (size_t)gi[p / g] * d);
      const float4* B = (const float4*)(yh + (size_t)gi[p % g] * d);
      const int per = (d / 4) / 4;
      for (int k = qq * per; k < (qq + 1) * per; ++k) {
        float4 a = A[k], b2 = B[k];
        float dx = a.x - b2.x, dy = a.y - b2.y, dz = a.z - b2.z, dw = a.w - b2.w;
        d2 += dx * dx + dy * dy + dz * dz + dw * dw;
      }
    }
    d2 += __shfl_down(d2, 2, 4);
    d2 += __shfl_down(d2, 1, 4);
    float v = (qq == 0 && p < npair) ? sqrtf(d2) : 0.f;
    red[t] = v;
    __syncthreads();
    for (int s = 128; s > 0; s >>= 1) {
      if (t < s) red[t] += red[t + s];
      __syncthreads();
    }
    if (t == 0) atomicAdd(h1, red[0] / (float)npair);
    return;
  }

  // ---- per-class 64x64 Gram tile ----
  const int w = b - G;
  if (w >= tstart[7]) return;
  int c = 0;
  while (c < 6 && w >= tstart[c + 1]) ++c;
  const int n = cnt[c];
  const int base = start[c];
  const int k = w - tstart[c];
  int by = (int)((sqrtf(8.f * (float)k + 1.f) - 1.f) * 0.5f);
  while ((by + 1) * (by + 2) / 2 <= k) ++by;
  while (by * (by + 1) / 2 > k) --by;
  const int bx = k - by * (by + 1) / 2;
  const float factor = (bx < by) ? 2.f : 1.f;

  const int wid = t >> 6, lane = t & 63;
  const int wr = wid >> 1, wc = wid & 1;
  const int srow = t >> 2, skc = (t & 3) * 8;
  const int fr = lane & 15, fq = lane >> 4;
  const int ar = by * 64 + srow, br = bx * 64 + srow;
  const short* Ap = ypb + (size_t)(base + ar) * d + skc;
  const short* Bp = ypb + (size_t)(base + br) * d + skc;
  const short8 z8 = {0, 0, 0, 0, 0, 0, 0, 0};

  short8 ca[2], cb[2];
#pragma unroll
  for (int h = 0; h < 2; ++h) {
    ca[h] = (ar < n) ? *(const short8*)(Ap + h * 32) : z8;
    cb[h] = (br < n) ? *(const short8*)(Bp + h * 32) : z8;
  }
  f32x4 acc[2][2] = {};
  for (int k0 = 0; k0 < d; k0 += 64) {  // d % 64 == 0
    short8 na[2] = {z8, z8}, nb[2] = {z8, z8};
    const int k1 = k0 + 64;
    if (k1 < d) {
#pragma unroll
      for (int h = 0; h < 2; ++h) {
        if (ar < n) na[h] = *(const short8*)(Ap + k1 + h * 32);
        if (br < n) nb[h] = *(const short8*)(Bp + k1 + h * 32);
      }
    }
    __syncthreads();
    *(short8*)&As[0][srow][skc] = ca[0];
    *(short8*)&As[1][srow][skc] = ca[1];
    *(short8*)&Bs[0][srow][skc] = cb[0];
    *(short8*)&Bs[1][srow][skc] = cb[1];
    __syncthreads();
#pragma unroll
    for (int h = 0; h < 2; ++h) {
      short8 af[2], bf[2];
      af[0] = *(const short8*)&As[h][wr * 32 + fr][fq * 8];
      af[1] = *(const short8*)&As[h][wr * 32 + 16 + fr][fq * 8];
      bf[0] = *(const short8*)&Bs[h][wc * 32 + fr][fq * 8];
      bf[1] = *(const short8*)&Bs[h][wc * 32 + 16 + fr][fq * 8];
#pragma unroll
      for (int mi = 0; mi < 2; ++mi)
#pragma unroll
        for (int ni = 0; ni < 2; ++ni)
          acc[mi][ni] = __builtin_amdgcn_mfma_f32_16x16x32_bf16(
              af[mi], bf[ni], acc[mi][ni], 0, 0, 0);
    }
    ca[0] = na[0]; ca[1] = na[1]; cb[0] = nb[0]; cb[1] = nb[1];
  }
  float sum = 0.f;
#pragma unroll
  for (int mi = 0; mi < 2; ++mi) {
#pragma unroll
    for (int j = 0; j < 4; ++j) {
      int ri = by * 64 + wr * 32 + mi * 16 + fq * 4 + j;
      if (ri >= n) continue;
      float si = sqp[base + ri];
#pragma unroll
      for (int ni = 0; ni < 2; ++ni) {
        int cj = bx * 64 + wc * 32 + ni * 16 + fr;
        if (cj >= n) continue;
        float d2 = si + sqp[base + cj] - 2.f * acc[mi][ni][j];
        sum += sqrtf(fmaxf(d2, 0.f));
      }
    }
  }
#pragma unroll
  for (int off = 32; off > 0; off >>= 1) sum += __shfl_down(sum, off);
  if (lane == 0) wred[wid] = sum;
  __syncthreads();
  if (t == 0)
    atomicAdd(&S[c], factor * (wred[0] + wred[1] + wred[2] + wred[3]));
}

__global__ void k_final(const float* __restrict__ C, int F,
    const float* __restrict__ S, const int* __restrict__ cnt,
    const float* __restrict__ h1, float* __restrict__ out, float beta) {
  float l1 = 0.f, l2 = 0.f;
  for (int f = 0; f < F; ++f) { float v = C[f]; l1 += fabsf(v); l2 += v * v; }
  l2 = sqrtf(l2);
  float dims = sqrtf((float)F);
  float sp = (dims - l1 / l2) / (dims - 1.f);
  float h2 = 0.f;
  for (int c = 0; c < 7; ++c) {
    if (cnt[c] > 0) { float cc = (float)cnt[c]; h2 += S[c] / (cc * cc); }
  }
  out[0] = sp + h2 - h1[0] / beta;
}

extern "C" void kernel_launch(void* const* d_in, const int* in_sizes, int n_in,
                              void* d_out, int out_size, void* d_ws, size_t ws_size,
                              hipStream_t stream) {
  const float* D = (const float*)d_in[0];
  const float* C = (const float*)d_in[1];
  const float* x = (const float*)d_in[2];
  const int* y = (const int*)d_in[3];
  const int* mask = (const int*)d_in[4];  // bool arrives widened to int32
  const int* groups = (const int*)d_in[5];
  float* out = (float*)d_out;

  const int N = in_sizes[3];            // 3000
  const int F = in_sizes[1];            // 14
  const int d = in_sizes[2] / N;        // 512
  const int G = in_sizes[5] / 7;        // 200 groups of g=7
  const long long NN = (long long)N * N;
  const long long NP = NN / 2;          // N even

  // workspace layout
  float* ws = (float*)d_ws;
  float* yh  = ws;                          // N*d
  float* sqp = yh + (size_t)N * d;          // N
  float* S   = sqp + N;                     // 8
  float* h1  = S + 8;                       // 8
  int* perm   = (int*)(h1 + 8);             // N
  int* cnt    = perm + N;                   // 8
  int* start  = cnt + 8;                    // 8
  int* tstart = start + 8;                  // 8
  short* Lb  = (short*)(((uintptr_t)(tstart + 8) + 15) & ~(uintptr_t)15);  // N*N
  short* xT  = Lb + NN;                     // d*N
  short* ypb = xT + (size_t)d * N;          // N*d

  const int nbG = 2048;                     // 8 blocks/CU streaming lhat
  const long long CPB = (NP + nbG - 1) / nbG;
  const int nbX = (d / 32) * ((N + 31) / 32);
  k_prep<<<dim3(nbG + nbX + 1), TB, 0, stream>>>(
      D, C, x, y, mask, Lb, xT, perm, cnt, start, tstart, S, h1,
      NP, N, d, CPB, nbG, nbX);
  {
    int nwg = ((N + 63) / 64) * (d / 64);  // 47 * 8 = 376
    k_yhat_mfma<<<dim3(nwg), TB, 0, stream>>>(Lb, xT, x, yh, N, d);
  }
  k_gather<<<dim3((N + 3) / 4), TB, 0, stream>>>(yh, perm, start, ypb, sqp, d);
  {
    int NB = (N + 63) / 64;
    int nbT = NB * (NB + 1) / 2;  // worst case: all rows in one class
    k_classh1<<<dim3(G + nbT), TB, 0, stream>>>(ypb, sqp, start, cnt, tstart,
                                                yh, groups, S, h1, d, G);
  }
  k_final<<<1, 1, 0, stream>>>(C, F, S, cnt, h1, out, (float)G / 7.0f);
}